// Round 5
// baseline (274.177 us; speedup 1.0000x reference)
//
#include <hip/hip_runtime.h>
#include <cstdint>

// BFP quantize: block = channel vector at each (n,h,w), NCHW layout.
// N=64, C=256, H=W=56, mantissa_bits=3.
// delta = 2^(e-3), max_abs = m*2^e, m in [0.5,1) (frexp). q = trunc(x/delta)*delta.
// Exact pow2 arithmetic — absmax==0 verified R1/R2/R3b.
//
// R5: R3b with PLAIN stores. nt-store (R4) broke L2 write-combining: each
// 4-lane group writes 64B of a 128B line; write-back stores merge in L2
// (WRITE=200MB), nt forced partial-line RMW (FETCH 579MB, WRITE 458MB, 272us).
// Low-register 2-sweep: pass A running abs-max (32 VGPR -> 8 waves/SIMD,
// 72% occupancy measured R4), butterfly shfl_xor across the 16 lanes/site,
// pass B re-read (L3-hit, proven R1) + quantize + normal store.

constexpr int C     = 256;
constexpr int HW    = 56 * 56;   // 3136
constexpr int HW4   = HW / 4;    // 784 float4 per (n,c) plane
constexpr int CHW4  = C * HW4;   // float4 per image
constexpr int CHUNK = 16;        // channels per lane (16 lanes cover C=256)

__device__ __forceinline__ int fexp(float x) {
    int e;
    (void)frexpf(x, &e);         // v_frexp_exp_i32_f32; e=0 for x==0
    return e;
}

__device__ __forceinline__ void fmax4(float4& m, const float4& v) {
    m.x = fmaxf(m.x, fabsf(v.x));
    m.y = fmaxf(m.y, fabsf(v.y));
    m.z = fmaxf(m.z, fabsf(v.z));
    m.w = fmaxf(m.w, fabsf(v.w));
}

__global__ __launch_bounds__(256, 8)
void bfp_kernel(const float4* __restrict__ in, float4* __restrict__ out, int total4) {
    int tid  = blockIdx.x * 256 + threadIdx.x;
    int wave = tid >> 6;
    int lane = threadIdx.x & 63;
    int s    = wave * 4 + (lane & 3);     // float4 spatial-site index
    if (s >= total4) return;
    int k    = lane >> 2;                 // channel chunk 0..15

    int n  = s / HW4;
    int s4 = s - n * HW4;

    const float4* p = in  + (size_t)n * CHW4 + (size_t)k * CHUNK * HW4 + s4;
    float4*       q = out + (size_t)n * CHW4 + (size_t)k * CHUNK * HW4 + s4;

    // ---- pass A: running abs-max over 16 channels, 4 accumulators for ILP ----
    float4 m0 = make_float4(0.f, 0.f, 0.f, 0.f), m1 = m0, m2 = m0, m3 = m0;
#pragma unroll
    for (int i = 0; i < CHUNK; i += 4) {
        float4 a = p[(i + 0) * HW4];
        float4 b = p[(i + 1) * HW4];
        float4 c = p[(i + 2) * HW4];
        float4 d = p[(i + 3) * HW4];
        fmax4(m0, a); fmax4(m1, b); fmax4(m2, c); fmax4(m3, d);
    }
    float4 m;
    m.x = fmaxf(fmaxf(m0.x, m1.x), fmaxf(m2.x, m3.x));
    m.y = fmaxf(fmaxf(m0.y, m1.y), fmaxf(m2.y, m3.y));
    m.z = fmaxf(fmaxf(m0.z, m1.z), fmaxf(m2.z, m3.z));
    m.w = fmaxf(fmaxf(m0.w, m1.w), fmaxf(m2.w, m3.w));

    // ---- butterfly reduce across the 16 lanes sharing this site ----
#pragma unroll
    for (int mask = 4; mask < 64; mask <<= 1) {
        m.x = fmaxf(m.x, __shfl_xor(m.x, mask));
        m.y = fmaxf(m.y, __shfl_xor(m.y, mask));
        m.z = fmaxf(m.z, __shfl_xor(m.z, mask));
        m.w = fmaxf(m.w, __shfl_xor(m.w, mask));
    }

    // ---- shared exponent -> delta = 2^(e-3), inv = 2^(3-e) (both exact) ----
    int ex = fexp(m.x), ey = fexp(m.y), ez = fexp(m.z), ew = fexp(m.w);
    float dx = ldexpf(1.f, ex - 3), ix = ldexpf(1.f, 3 - ex);
    float dy = ldexpf(1.f, ey - 3), iy = ldexpf(1.f, 3 - ey);
    float dz = ldexpf(1.f, ez - 3), iz = ldexpf(1.f, 3 - ez);
    float dw = ldexpf(1.f, ew - 3), iw = ldexpf(1.f, 3 - ew);

    // ---- pass B: re-read (L3-hit), quantize, normal write-back store ----
#pragma unroll
    for (int i = 0; i < CHUNK; ++i) {
        float4 v = p[i * HW4];
        float4 r;
        r.x = truncf(v.x * ix) * dx;
        r.y = truncf(v.y * iy) * dy;
        r.z = truncf(v.z * iz) * dz;
        r.w = truncf(v.w * iw) * dw;
        q[i * HW4] = r;
    }
}

extern "C" void kernel_launch(void* const* d_in, const int* in_sizes, int n_in,
                              void* d_out, int out_size, void* d_ws, size_t ws_size,
                              hipStream_t stream) {
    const float* in = (const float*)d_in[0];
    float* out      = (float*)d_out;
    int N      = in_sizes[0] / (C * HW);        // 64
    int total4 = N * HW4;                       // 50176 float4 sites
    int waves  = (total4 + 3) / 4;              // 4 sites per wave
    int blocks = (waves + 3) / 4;               // 4 waves per 256-thread block
    bfp_kernel<<<blocks, 256, 0, stream>>>((const float4*)in, (float4*)out, total4);
}

// Round 6
// 81.588 us; speedup vs baseline: 3.3605x; 3.3605x over previous
//
#include <hip/hip_runtime.h>
#include <cstdint>

// BFP quantize: block = channel vector at each (n,h,w), NCHW layout.
// N=64, C=256, H=W=56, mantissa_bits=3.
// delta = 2^(e-3), max_abs = m*2^e, m in [0.5,1) (frexp). q = trunc(x/delta)*delta.
// Exact pow2 arithmetic — absmax==0 verified R1/R2/R3b/R5.
//
// R6: full-line access pattern. R2/R4/R5 all used 4-lane (64B) chunks per
// channel -> half-line accesses whose pairing in L2 fails under wave drift:
// measured FETCH 601MB (2.9x), WRITE 445MB (2.2x). R1's 1KB-contiguous
// accesses measured exactly 1.0x. Fix: lane l -> site j=l&7 (8 float4 = one
// FULL aligned 128B line; channel stride 12544B = 98 lines), channel group
// g=l>>3; 4 waves split 256 channels (c = w*64 + g*8 + i, 8 regs/lane).
// Single read (register-resident), shfl_xor reduce over g + 512B LDS reduce
// over waves, quantize from regs, single full-line write. No L3 reliance.

constexpr int C    = 256;
constexpr int HW   = 56 * 56;   // 3136
constexpr int HW4  = HW / 4;    // 784 float4 per (n,c) plane (div by 8)
constexpr int CHW4 = C * HW4;   // float4 per image

__device__ __forceinline__ int fexp(float x) {
    int e;
    (void)frexpf(x, &e);         // v_frexp_exp_i32_f32; e=0 for x==0
    return e;
}

__device__ __forceinline__ void fmax4(float4& m, const float4& v) {
    m.x = fmaxf(m.x, fabsf(v.x));
    m.y = fmaxf(m.y, fabsf(v.y));
    m.z = fmaxf(m.z, fabsf(v.z));
    m.w = fmaxf(m.w, fabsf(v.w));
}

__global__ __launch_bounds__(256, 8)
void bfp_kernel(const float4* __restrict__ in, float4* __restrict__ out) {
    const int l = threadIdx.x & 63;   // lane
    const int w = threadIdx.x >> 6;   // wave 0..3
    const int j = l & 7;              // site offset within block's 8 sites
    const int g = l >> 3;             // channel sub-group 0..7

    const int s  = blockIdx.x * 8 + j;      // float4 site (grid exact: HW4%8==0)
    const int n  = s / HW4;
    const int s4 = s - n * HW4;
    const int c0 = w * 64 + g * 8;          // first of this lane's 8 channels

    const float4* p = in  + (size_t)n * CHW4 + (size_t)c0 * HW4 + s4;
    float4*       q = out + (size_t)n * CHW4 + (size_t)c0 * HW4 + s4;

    // ---- single global read: 8 channels into registers (static unroll) ----
    float4 v0 = p[0 * HW4], v1 = p[1 * HW4], v2 = p[2 * HW4], v3 = p[3 * HW4];
    float4 v4 = p[4 * HW4], v5 = p[5 * HW4], v6 = p[6 * HW4], v7 = p[7 * HW4];

    // ---- per-lane abs-max (pairwise tree for ILP) ----
    float4 a0 = make_float4(0.f, 0.f, 0.f, 0.f), a1 = a0, a2 = a0, a3 = a0;
    fmax4(a0, v0); fmax4(a1, v1); fmax4(a2, v2); fmax4(a3, v3);
    fmax4(a0, v4); fmax4(a1, v5); fmax4(a2, v6); fmax4(a3, v7);
    float4 m;
    m.x = fmaxf(fmaxf(a0.x, a1.x), fmaxf(a2.x, a3.x));
    m.y = fmaxf(fmaxf(a0.y, a1.y), fmaxf(a2.y, a3.y));
    m.z = fmaxf(fmaxf(a0.z, a1.z), fmaxf(a2.z, a3.z));
    m.w = fmaxf(fmaxf(a0.w, a1.w), fmaxf(a2.w, a3.w));

    // ---- butterfly across the 8 channel-groups (lanes sharing site j) ----
#pragma unroll
    for (int mask = 8; mask < 64; mask <<= 1) {
        m.x = fmaxf(m.x, __shfl_xor(m.x, mask));
        m.y = fmaxf(m.y, __shfl_xor(m.y, mask));
        m.z = fmaxf(m.z, __shfl_xor(m.z, mask));
        m.w = fmaxf(m.w, __shfl_xor(m.w, mask));
    }

    // ---- cross-wave reduce via tiny LDS (4 waves x 8 sites x float4) ----
    __shared__ float4 red[4][8];
    if (g == 0) red[w][j] = m;
    __syncthreads();
    float4 M = red[0][j];
    fmax4(M, red[1][j]);   // fmax4 takes fabs — values already >=0, harmless
    fmax4(M, red[2][j]);
    fmax4(M, red[3][j]);

    // ---- shared exponent -> delta = 2^(e-3), inv = 2^(3-e) (both exact) ----
    const int ex = fexp(M.x), ey = fexp(M.y), ez = fexp(M.z), ew = fexp(M.w);
    const float dx = ldexpf(1.f, ex - 3), ix = ldexpf(1.f, 3 - ex);
    const float dy = ldexpf(1.f, ey - 3), iy = ldexpf(1.f, 3 - ey);
    const float dz = ldexpf(1.f, ez - 3), iz = ldexpf(1.f, 3 - ez);
    const float dw = ldexpf(1.f, ew - 3), iw = ldexpf(1.f, 3 - ew);

    // ---- quantize from registers, single full-line write ----
#define QSTORE(idx, vv)                                   \
    {                                                     \
        float4 r;                                         \
        r.x = truncf(vv.x * ix) * dx;                     \
        r.y = truncf(vv.y * iy) * dy;                     \
        r.z = truncf(vv.z * iz) * dz;                     \
        r.w = truncf(vv.w * iw) * dw;                     \
        q[idx * HW4] = r;                                 \
    }
    QSTORE(0, v0) QSTORE(1, v1) QSTORE(2, v2) QSTORE(3, v3)
    QSTORE(4, v4) QSTORE(5, v5) QSTORE(6, v6) QSTORE(7, v7)
#undef QSTORE
}

extern "C" void kernel_launch(void* const* d_in, const int* in_sizes, int n_in,
                              void* d_out, int out_size, void* d_ws, size_t ws_size,
                              hipStream_t stream) {
    const float* in = (const float*)d_in[0];
    float* out      = (float*)d_out;
    int N      = in_sizes[0] / (C * HW);   // 64
    int total4 = N * HW4;                  // 50176 float4 sites (divisible by 8)
    int blocks = total4 / 8;               // 6272 blocks of 256 threads
    bfp_kernel<<<blocks, 256, 0, stream>>>((const float4*)in, (float4*)out);
}